// Round 2
// baseline (100.421 us; speedup 1.0000x reference)
//
#include <hip/hip_runtime.h>
#include <hip/hip_bf16.h>
#include <cstdint>

#define B_ROWS 8192
#define DIM    1024
#define NC     8
#define NXCD   8
#define SLOTS  16   // per-XCD row-tile slots (16*128 = 2048 rows/condition before spill)

typedef __bf16 bf16;
typedef __bf16 bf16x8 __attribute__((ext_vector_type(8)));
typedef float  f32x4  __attribute__((ext_vector_type(4)));

typedef __attribute__((address_space(3))) void* lds_vp;
typedef const __attribute__((address_space(1))) void* gbl_vp;

// ---------------- route: bucket rows, per-XCD tile lists, bias_sum ---------
// xmeta[(x*SLOTS+s)*3 + {0,1,2}] = {cond, rstart, rcnt}; rcnt==0 -> empty slot
__global__ void route_kernel(const int* __restrict__ ids, const float* __restrict__ b,
                             int* __restrict__ row_list, int* __restrict__ xmeta,
                             float* __restrict__ bias_sum) {
    __shared__ int cnt[NC];
    __shared__ int off[NC];
    int tid = threadIdx.x;
    if (tid < NC) cnt[tid] = 0;
    __syncthreads();

    int local[NC];
#pragma unroll
    for (int c = 0; c < NC; c++) local[c] = 0;
    const int per = B_ROWS / 256;  // 32
    int base = tid * per;
    for (int j = 0; j < per; j++) local[ids[base + j]]++;
    int mybase[NC];
#pragma unroll
    for (int c = 0; c < NC; c++) mybase[c] = atomicAdd(&cnt[c], local[c]);
    __syncthreads();

    if (tid == 0) {
        int fill[NXCD];
        for (int x = 0; x < NXCD; x++) fill[x] = 0;
        for (int i = 0; i < NXCD * SLOTS; i++) xmeta[i * 3 + 2] = 0;
        int acc = 0;
        for (int c = 0; c < NC; c++) {
            off[c] = acc;
            int n = cnt[c];
            int t = 0;
            while (t * 128 < n) {
                int rc = n - t * 128; if (rc > 128) rc = 128;
                int x = c;  // condition c pinned to XCD c
                if (fill[x] >= SLOTS) {  // spill anywhere with space (correctness > locality)
                    for (int xx = 0; xx < NXCD; xx++) if (fill[xx] < SLOTS) { x = xx; break; }
                }
                int s = fill[x]++;
                int* e = xmeta + (x * SLOTS + s) * 3;
                e[0] = c; e[1] = acc + t * 128; e[2] = rc;
                t++;
            }
            acc += n;
        }
    }
    __syncthreads();

    // bias_sum[d] = sum_c b[c][d]   (1024 dims / 256 threads = 4 each)
#pragma unroll
    for (int k = 0; k < DIM / 256; k++) {
        int d = tid + k * 256;
        float s = 0.f;
#pragma unroll
        for (int c = 0; c < NC; c++) s += b[c * DIM + d];
        bias_sum[d] = s;
    }

    int pos[NC];
#pragma unroll
    for (int c = 0; c < NC; c++) pos[c] = off[c] + mybase[c];
    for (int j = 0; j < per; j++) {
        int id = ids[base + j];
        row_list[pos[id]++] = base + j;
    }
}

// ---------------- prep: gathered x->bf16, pad-zero, W->bf16 ----------------
#define XCH   (B_ROWS * DIM / 8)        // 1048576 chunks of 8
#define PADCH (128 * DIM / 8)           // 16384
#define WCH   (NC * DIM * DIM / 8)      // 1048576
__global__ void prep_kernel(const float* __restrict__ x, const float* __restrict__ W,
                            const int* __restrict__ row_list,
                            bf16* __restrict__ xg, bf16* __restrict__ wb) {
    const int total = XCH + PADCH + WCH;
    for (int i = blockIdx.x * blockDim.x + threadIdx.x; i < total; i += gridDim.x * blockDim.x) {
        if (i < XCH) {
            int r = i >> 7, cc = i & 127;         // 128 chunks per row
            int src = row_list[r];
            const float4* s = (const float4*)(x + (size_t)src * DIM + cc * 8);
            float4 a = s[0], bb = s[1];
            bf16x8 o;
            o[0] = (bf16)a.x; o[1] = (bf16)a.y; o[2] = (bf16)a.z; o[3] = (bf16)a.w;
            o[4] = (bf16)bb.x; o[5] = (bf16)bb.y; o[6] = (bf16)bb.z; o[7] = (bf16)bb.w;
            *(bf16x8*)(xg + (size_t)r * DIM + cc * 8) = o;
        } else if (i < XCH + PADCH) {
            int j = i - XCH;
            *(bf16x8*)(xg + (size_t)B_ROWS * DIM + 8 * (size_t)j) = (bf16x8){};
        } else {
            int j = i - XCH - PADCH;
            const float4* s = (const float4*)W + 2 * (size_t)j;
            float4 a = s[0], bb = s[1];
            bf16x8 o;
            o[0] = (bf16)a.x; o[1] = (bf16)a.y; o[2] = (bf16)a.z; o[3] = (bf16)a.w;
            o[4] = (bf16)bb.x; o[5] = (bf16)bb.y; o[6] = (bf16)bb.z; o[7] = (bf16)bb.w;
            *(bf16x8*)(wb + 8 * (size_t)j) = o;
        }
    }
}

// ---------------- grouped GEMM: 128x128 tile, BK=64, 2-phase LDS dbuf ------
__global__ __launch_bounds__(256, 2) void gemm_kernel(
    const bf16* __restrict__ xg, const bf16* __restrict__ wb,
    const float* __restrict__ bias_sum, const int* __restrict__ row_list,
    const int* __restrict__ xmeta, float* __restrict__ out) {
    int xcd = blockIdx.x, slot = blockIdx.y, colt = blockIdx.z;
    const int* e = xmeta + (xcd * SLOTS + slot) * 3;
    int cond = e[0], rstart = e[1], rcnt = e[2];
    if (rcnt == 0) return;
    int col0 = colt * 128;

    __shared__ bf16 lds[2][2][128 * 64];  // [buf][A/B][row*64+k], 64 KB

    int tid  = threadIdx.x;
    int lane = tid & 63;
    int w    = tid >> 6;
    int wr   = w >> 1;
    int wc   = w & 1;
    int srow = lane >> 3;            // 0..7
    int scol = (lane & 7) * 8;       // 16B granules across K

    const bf16 *aS[4], *bS[4];
#pragma unroll
    for (int i = 0; i < 4; i++) {
        int tr = w * 32 + i * 8 + srow;                       // tile row 0..127
        aS[i] = xg + (size_t)(rstart + tr) * DIM + scol;      // pre-gathered rows
        bS[i] = wb + (size_t)cond * DIM * DIM + (size_t)(col0 + tr) * DIM + scol;
    }

    f32x4 acc[4][4];
#pragma unroll
    for (int m = 0; m < 4; m++)
#pragma unroll
        for (int n = 0; n < 4; n++) acc[m][n] = (f32x4){0.f, 0.f, 0.f, 0.f};

    int fr = lane & 15;
    int fq = lane >> 4;

    auto stage = [&](int buf, int k0) {
#pragma unroll
        for (int i = 0; i < 4; i++) {
            __builtin_amdgcn_global_load_lds((gbl_vp)(aS[i] + k0),
                                             (lds_vp)(&lds[buf][0][(w * 32 + i * 8) * 64]),
                                             16, 0, 0);
            __builtin_amdgcn_global_load_lds((gbl_vp)(bS[i] + k0),
                                             (lds_vp)(&lds[buf][1][(w * 32 + i * 8) * 64]),
                                             16, 0, 0);
        }
    };

    stage(0, 0);
    __syncthreads();  // drains vmcnt(0) before barrier

    int cur = 0;
    const int NT = DIM / 64;  // 16
    for (int t = 0; t < NT; ++t) {
        if (t + 1 < NT) stage(cur ^ 1, (t + 1) * 64);  // prefetch overlaps compute below
        const bf16* lA = &lds[cur][0][(wr * 64 + fr) * 64 + fq * 8];
        const bf16* lB = &lds[cur][1][(wc * 64 + fr) * 64 + fq * 8];
#pragma unroll
        for (int kk = 0; kk < 2; ++kk) {
            bf16x8 af[4], bv[4];
#pragma unroll
            for (int m = 0; m < 4; m++) af[m] = *(const bf16x8*)(lA + m * 16 * 64 + kk * 32);
#pragma unroll
            for (int n = 0; n < 4; n++) bv[n] = *(const bf16x8*)(lB + n * 16 * 64 + kk * 32);
#pragma unroll
            for (int m = 0; m < 4; m++)
#pragma unroll
                for (int n = 0; n < 4; n++)
                    acc[m][n] = __builtin_amdgcn_mfma_f32_16x16x32_bf16(
                        af[m], bv[n], acc[m][n], 0, 0, 0);
        }
        __syncthreads();  // single barrier: drains prefetch vmcnt + syncs LDS reuse
        cur ^= 1;
    }

    // epilogue: + bias, scatter rows back through row_list
    float bias[4];
#pragma unroll
    for (int n = 0; n < 4; n++) bias[n] = bias_sum[col0 + wc * 64 + n * 16 + fr];
#pragma unroll
    for (int m = 0; m < 4; m++) {
#pragma unroll
        for (int i = 0; i < 4; i++) {
            int rl = wr * 64 + m * 16 + fq * 4 + i;
            if (rl < rcnt) {
                int grow = row_list[rstart + rl];
                float* op = out + (size_t)grow * DIM + col0 + wc * 64 + fr;
#pragma unroll
                for (int n = 0; n < 4; n++) op[n * 16] = acc[m][n][i] + bias[n];
            }
        }
    }
}

// ---------------- naive fallback (only if ws too small) --------------------
__global__ void naive_kernel(const float* __restrict__ x, const int* __restrict__ ids,
                             const float* __restrict__ W, const float* __restrict__ b,
                             float* __restrict__ out) {
    int row = blockIdx.x;
    int c = ids[row];
    __shared__ float xs[DIM];
    for (int i = threadIdx.x; i < DIM; i += 256) xs[i] = x[(size_t)row * DIM + i];
    __syncthreads();
    const float* Wc = W + (size_t)c * DIM * DIM;
    for (int o = threadIdx.x; o < DIM; o += 256) {
        float s = 0.f;
        const float* wrp = Wc + (size_t)o * DIM;
        for (int i = 0; i < DIM; i++) s += xs[i] * wrp[i];
        float bs = 0.f;
#pragma unroll
        for (int cc = 0; cc < NC; cc++) bs += b[cc * DIM + o];
        out[(size_t)row * DIM + o] = s + bs;
    }
}

extern "C" void kernel_launch(void* const* d_in, const int* in_sizes, int n_in,
                              void* d_out, int out_size, void* d_ws, size_t ws_size,
                              hipStream_t stream) {
    const float* x   = (const float*)d_in[0];
    const int*   ids = (const int*)d_in[1];
    const float* W   = (const float*)d_in[2];
    const float* b   = (const float*)d_in[3];
    float*       out = (float*)d_out;

    size_t xg_off   = 0;
    size_t xg_sz    = (size_t)(B_ROWS + 128) * DIM * 2;       // gathered bf16 x + pad
    size_t wb_off   = (xg_off + xg_sz + 255) & ~(size_t)255;
    size_t wb_sz    = (size_t)NC * DIM * DIM * 2;
    size_t bias_off = (wb_off + wb_sz + 255) & ~(size_t)255;
    size_t rl_off   = (bias_off + DIM * 4 + 255) & ~(size_t)255;
    size_t meta_off = (rl_off + B_ROWS * 4 + 255) & ~(size_t)255;
    size_t need     = meta_off + (size_t)NXCD * SLOTS * 3 * 4;

    if (ws_size < need) {  // emergency correct-but-slow path
        naive_kernel<<<dim3(B_ROWS), dim3(256), 0, stream>>>(x, ids, W, b, out);
        return;
    }

    char* ws = (char*)d_ws;
    bf16*  xg       = (bf16*)(ws + xg_off);
    bf16*  wbf      = (bf16*)(ws + wb_off);
    float* bias_sum = (float*)(ws + bias_off);
    int*   row_list = (int*)(ws + rl_off);
    int*   xmeta    = (int*)(ws + meta_off);

    route_kernel<<<dim3(1), dim3(256), 0, stream>>>(ids, b, row_list, xmeta, bias_sum);
    prep_kernel<<<dim3(2048), dim3(256), 0, stream>>>(x, W, row_list, xg, wbf);
    gemm_kernel<<<dim3(NXCD, SLOTS, 8), dim3(256), 0, stream>>>(xg, wbf, bias_sum, row_list, xmeta, out);
}

// Round 3
// 89.678 us; speedup vs baseline: 1.1198x; 1.1198x over previous
//
#include <hip/hip_runtime.h>
#include <hip/hip_bf16.h>
#include <cstdint>

#define B_ROWS 8192
#define DIM    1024
#define NC     8
#define NXCD   8
#define SLOTS  16   // per-XCD row-tile slots

typedef __bf16 bf16;
typedef __bf16 bf16x8 __attribute__((ext_vector_type(8)));
typedef float  f32x4  __attribute__((ext_vector_type(4)));

typedef __attribute__((address_space(3))) void* lds_vp;
typedef const __attribute__((address_space(1))) void* gbl_vp;

// ---------------- route: bucket rows, per-XCD tile lists, bias_sum ---------
__global__ void route_kernel(const int* __restrict__ ids, const float* __restrict__ b,
                             int* __restrict__ row_list, int* __restrict__ xmeta,
                             float* __restrict__ bias_sum) {
    __shared__ int cnt[NC];
    __shared__ int off[NC];
    int tid = threadIdx.x;
    if (tid < NC) cnt[tid] = 0;
    __syncthreads();

    int local[NC];
#pragma unroll
    for (int c = 0; c < NC; c++) local[c] = 0;
    const int per = B_ROWS / 256;  // 32
    int base = tid * per;
    for (int j = 0; j < per; j++) local[ids[base + j]]++;
    int mybase[NC];
#pragma unroll
    for (int c = 0; c < NC; c++) mybase[c] = atomicAdd(&cnt[c], local[c]);
    __syncthreads();

    if (tid == 0) {
        int fill[NXCD];
        for (int x = 0; x < NXCD; x++) fill[x] = 0;
        for (int i = 0; i < NXCD * SLOTS; i++) xmeta[i * 3 + 2] = 0;
        int acc = 0;
        for (int c = 0; c < NC; c++) {
            off[c] = acc;
            int n = cnt[c];
            int t = 0;
            while (t * 128 < n) {
                int rc = n - t * 128; if (rc > 128) rc = 128;
                int x = c;
                if (fill[x] >= SLOTS) {
                    for (int xx = 0; xx < NXCD; xx++) if (fill[xx] < SLOTS) { x = xx; break; }
                }
                int s = fill[x]++;
                int* e = xmeta + (x * SLOTS + s) * 3;
                e[0] = c; e[1] = acc + t * 128; e[2] = rc;
                t++;
            }
            acc += n;
        }
    }
    __syncthreads();

#pragma unroll
    for (int k = 0; k < DIM / 256; k++) {
        int d = tid + k * 256;
        float s = 0.f;
#pragma unroll
        for (int c = 0; c < NC; c++) s += b[c * DIM + d];
        bias_sum[d] = s;
    }

    int pos[NC];
#pragma unroll
    for (int c = 0; c < NC; c++) pos[c] = off[c] + mybase[c];
    for (int j = 0; j < per; j++) {
        int id = ids[base + j];
        row_list[pos[id]++] = base + j;
    }
}

// ---------------- prep: gathered x->bf16, pad-zero, W->bf16 ----------------
#define XCH   (B_ROWS * DIM / 8)
#define PADCH (128 * DIM / 8)
#define WCH   (NC * DIM * DIM / 8)
__global__ void prep_kernel(const float* __restrict__ x, const float* __restrict__ W,
                            const int* __restrict__ row_list,
                            bf16* __restrict__ xg, bf16* __restrict__ wb) {
    const int total = XCH + PADCH + WCH;
    for (int i = blockIdx.x * blockDim.x + threadIdx.x; i < total; i += gridDim.x * blockDim.x) {
        if (i < XCH) {
            int r = i >> 7, cc = i & 127;
            int src = row_list[r];
            const float4* s = (const float4*)(x + (size_t)src * DIM + cc * 8);
            float4 a = s[0], bb = s[1];
            bf16x8 o;
            o[0] = (bf16)a.x; o[1] = (bf16)a.y; o[2] = (bf16)a.z; o[3] = (bf16)a.w;
            o[4] = (bf16)bb.x; o[5] = (bf16)bb.y; o[6] = (bf16)bb.z; o[7] = (bf16)bb.w;
            *(bf16x8*)(xg + (size_t)r * DIM + cc * 8) = o;
        } else if (i < XCH + PADCH) {
            int j = i - XCH;
            *(bf16x8*)(xg + (size_t)B_ROWS * DIM + 8 * (size_t)j) = (bf16x8){};
        } else {
            int j = i - XCH - PADCH;
            const float4* s = (const float4*)W + 2 * (size_t)j;
            float4 a = s[0], bb = s[1];
            bf16x8 o;
            o[0] = (bf16)a.x; o[1] = (bf16)a.y; o[2] = (bf16)a.z; o[3] = (bf16)a.w;
            o[4] = (bf16)bb.x; o[5] = (bf16)bb.y; o[6] = (bf16)bb.z; o[7] = (bf16)bb.w;
            *(bf16x8*)(wb + 8 * (size_t)j) = o;
        }
    }
}

// ---------------- grouped GEMM: 128x128, BK=64, counted-vmcnt 2-phase ------
// LDS layout: lds[buf][A/B][row][64] with XOR swizzle: LDS slot (r, cb16)
// holds global col (cb16 ^ (r&7)); staged via pre-swizzled global source.
__global__ __launch_bounds__(256, 2) void gemm_kernel(
    const bf16* __restrict__ xg, const bf16* __restrict__ wb,
    const float* __restrict__ bias_sum, const int* __restrict__ row_list,
    const int* __restrict__ xmeta, float* __restrict__ out) {
    int xcd = blockIdx.x, slot = blockIdx.y, colt = blockIdx.z;
    const int* e = xmeta + (xcd * SLOTS + slot) * 3;
    int cond = e[0], rstart = e[1], rcnt = e[2];
    if (rcnt == 0) return;
    int col0 = colt * 128;

    __shared__ bf16 lds[2][2][128 * 64];  // 64 KB

    int tid  = threadIdx.x;
    int lane = tid & 63;
    int w    = tid >> 6;
    int wr   = w >> 1;
    int wc   = w & 1;
    int srow = lane >> 3;                       // 0..7
    int scol = ((lane & 7) ^ srow) * 8;         // swizzled global source col (elems)

    const bf16 *aS[4], *bS[4];
#pragma unroll
    for (int i = 0; i < 4; i++) {
        int tr = w * 32 + i * 8 + srow;
        aS[i] = xg + (size_t)(rstart + tr) * DIM + scol;
        bS[i] = wb + (size_t)cond * DIM * DIM + (size_t)(col0 + tr) * DIM + scol;
    }

    f32x4 acc[4][4];
#pragma unroll
    for (int m = 0; m < 4; m++)
#pragma unroll
        for (int n = 0; n < 4; n++) acc[m][n] = (f32x4){0.f, 0.f, 0.f, 0.f};

    int fr = lane & 15;
    int fq = lane >> 4;
    int off0 = (fq * 16) ^ ((fr & 7) << 4);   // swizzled byte offset, kk=0
    int off1 = off0 ^ 64;                     // kk=1

    auto stage = [&](int buf, int k0) {
#pragma unroll
        for (int i = 0; i < 4; i++) {
            __builtin_amdgcn_global_load_lds((gbl_vp)(aS[i] + k0),
                                             (lds_vp)(&lds[buf][0][(w * 32 + i * 8) * 64]),
                                             16, 0, 0);
            __builtin_amdgcn_global_load_lds((gbl_vp)(bS[i] + k0),
                                             (lds_vp)(&lds[buf][1][(w * 32 + i * 8) * 64]),
                                             16, 0, 0);
        }
    };

    stage(0, 0);
    stage(1, 64);   // 16 loads in flight

    const int NT = DIM / 64;  // 16
    for (int t = 0; t < NT; ++t) {
        // wait for tile t's 8 loads (tile t+1's 8 stay in flight)
        if (t < NT - 1) asm volatile("s_waitcnt vmcnt(8)" ::: "memory");
        else            asm volatile("s_waitcnt vmcnt(0)" ::: "memory");
        __builtin_amdgcn_s_barrier();

        const char* baseA = (const char*)&lds[t & 1][0][0] + (wr * 64 + fr) * 128;
        const char* baseB = (const char*)&lds[t & 1][1][0] + (wc * 64 + fr) * 128;
#pragma unroll
        for (int kk = 0; kk < 2; ++kk) {
            int ofs = kk ? off1 : off0;
            bf16x8 af[4], bv[4];
#pragma unroll
            for (int m = 0; m < 4; m++) af[m] = *(const bf16x8*)(baseA + m * 2048 + ofs);
#pragma unroll
            for (int n = 0; n < 4; n++) bv[n] = *(const bf16x8*)(baseB + n * 2048 + ofs);
            __builtin_amdgcn_s_setprio(1);
#pragma unroll
            for (int m = 0; m < 4; m++)
#pragma unroll
                for (int n = 0; n < 4; n++)
                    acc[m][n] = __builtin_amdgcn_mfma_f32_16x16x32_bf16(
                        af[m], bv[n], acc[m][n], 0, 0, 0);
            __builtin_amdgcn_s_setprio(0);
        }

        asm volatile("s_waitcnt lgkmcnt(0)" ::: "memory");  // my LDS reads retired
        __builtin_amdgcn_s_barrier();                        // everyone done with buf t&1
        if (t + 2 < NT) stage(t & 1, (t + 2) * 64);          // overwrite it with tile t+2
    }

    float bias[4];
#pragma unroll
    for (int n = 0; n < 4; n++) bias[n] = bias_sum[col0 + wc * 64 + n * 16 + fr];
#pragma unroll
    for (int m = 0; m < 4; m++) {
#pragma unroll
        for (int i = 0; i < 4; i++) {
            int rl = wr * 64 + m * 16 + fq * 4 + i;
            if (rl < rcnt) {
                int grow = row_list[rstart + rl];
                float* op = out + (size_t)grow * DIM + col0 + wc * 64 + fr;
#pragma unroll
                for (int n = 0; n < 4; n++) op[n * 16] = acc[m][n][i] + bias[n];
            }
        }
    }
}

// ---------------- naive fallback (only if ws too small) --------------------
__global__ void naive_kernel(const float* __restrict__ x, const int* __restrict__ ids,
                             const float* __restrict__ W, const float* __restrict__ b,
                             float* __restrict__ out) {
    int row = blockIdx.x;
    int c = ids[row];
    __shared__ float xs[DIM];
    for (int i = threadIdx.x; i < DIM; i += 256) xs[i] = x[(size_t)row * DIM + i];
    __syncthreads();
    const float* Wc = W + (size_t)c * DIM * DIM;
    for (int o = threadIdx.x; o < DIM; o += 256) {
        float s = 0.f;
        const float* wrp = Wc + (size_t)o * DIM;
        for (int i = 0; i < DIM; i++) s += xs[i] * wrp[i];
        float bs = 0.f;
#pragma unroll
        for (int cc = 0; cc < NC; cc++) bs += b[cc * DIM + o];
        out[(size_t)row * DIM + o] = s + bs;
    }
}

extern "C" void kernel_launch(void* const* d_in, const int* in_sizes, int n_in,
                              void* d_out, int out_size, void* d_ws, size_t ws_size,
                              hipStream_t stream) {
    const float* x   = (const float*)d_in[0];
    const int*   ids = (const int*)d_in[1];
    const float* W   = (const float*)d_in[2];
    const float* b   = (const float*)d_in[3];
    float*       out = (float*)d_out;

    size_t xg_off   = 0;
    size_t xg_sz    = (size_t)(B_ROWS + 128) * DIM * 2;
    size_t wb_off   = (xg_off + xg_sz + 255) & ~(size_t)255;
    size_t wb_sz    = (size_t)NC * DIM * DIM * 2;
    size_t bias_off = (wb_off + wb_sz + 255) & ~(size_t)255;
    size_t rl_off   = (bias_off + DIM * 4 + 255) & ~(size_t)255;
    size_t meta_off = (rl_off + B_ROWS * 4 + 255) & ~(size_t)255;
    size_t need     = meta_off + (size_t)NXCD * SLOTS * 3 * 4;

    if (ws_size < need) {
        naive_kernel<<<dim3(B_ROWS), dim3(256), 0, stream>>>(x, ids, W, b, out);
        return;
    }

    char* ws = (char*)d_ws;
    bf16*  xg       = (bf16*)(ws + xg_off);
    bf16*  wbf      = (bf16*)(ws + wb_off);
    float* bias_sum = (float*)(ws + bias_off);
    int*   row_list = (int*)(ws + rl_off);
    int*   xmeta    = (int*)(ws + meta_off);

    route_kernel<<<dim3(1), dim3(256), 0, stream>>>(ids, b, row_list, xmeta, bias_sum);
    prep_kernel<<<dim3(2048), dim3(256), 0, stream>>>(x, W, row_list, xg, wbf);
    gemm_kernel<<<dim3(NXCD, SLOTS, 8), dim3(256), 0, stream>>>(xg, wbf, bias_sum, row_list, xmeta, out);
}

// Round 4
// 82.167 us; speedup vs baseline: 1.2222x; 1.0914x over previous
//
#include <hip/hip_runtime.h>
#include <hip/hip_bf16.h>
#include <cstdint>

#define B_ROWS 8192
#define DIM    1024
#define NC     8
#define NXCD   8
#define SLOTS  16   // per-XCD row-tile slots

typedef __bf16 bf16;
typedef __bf16 bf16x8 __attribute__((ext_vector_type(8)));
typedef float  f32x4  __attribute__((ext_vector_type(4)));

typedef __attribute__((address_space(3))) void* lds_vp;
typedef const __attribute__((address_space(1))) void* gbl_vp;

// ---------------- fused prep: block 0 routes, blocks 1.. convert -----------
#define XCH (B_ROWS * DIM / 8)
#define WCH (NC * DIM * DIM / 8)

__global__ void prep_kernel(const float* __restrict__ x, const float* __restrict__ W,
                            const int* __restrict__ ids, const float* __restrict__ b,
                            bf16* __restrict__ xb, bf16* __restrict__ wb,
                            int* __restrict__ row_list, int* __restrict__ xmeta,
                            float* __restrict__ bias_sum) {
    if (blockIdx.x == 0) {
        // ---------- routing: no atomics, no scratch arrays ----------
        __shared__ int cnt_s[NC];
        __shared__ int off_s[NC];
        __shared__ int wbase_s[4][NC];
        __shared__ int used_s[NXCD];
        __shared__ int novf_s[NC];
        int tid = threadIdx.x, lane = tid & 63, wv = tid >> 6;
        const int per = B_ROWS / 256;  // 32
        int base = tid * per;

        // zero all xmeta rcnt fields (overwritten below for live slots)
        if (tid < NXCD * SLOTS) xmeta[tid * 3 + 2] = 0;

        // count my 32 ids into packed 16-bit fields (conds 0-3 -> p0, 4-7 -> p1)
        int myid[32];
        unsigned long long p0 = 0, p1 = 0;
        const int4* idv = (const int4*)(ids + base);
#pragma unroll
        for (int j = 0; j < 8; j++) {
            int4 v = idv[j];
            myid[4 * j + 0] = v.x; myid[4 * j + 1] = v.y;
            myid[4 * j + 2] = v.z; myid[4 * j + 3] = v.w;
#pragma unroll
            for (int q = 0; q < 4; q++) {
                int id = myid[4 * j + q];
                unsigned long long one = 1ull << ((id & 3) << 4);
                if (id < 4) p0 += one; else p1 += one;
            }
        }
        // inclusive scan across the wave (field-wise; wave sums <= 2048 < 2^16)
        unsigned long long i0 = p0, i1 = p1;
#pragma unroll
        for (int d = 1; d < 64; d <<= 1) {
            unsigned long long u0 = __shfl_up(i0, d, 64);
            unsigned long long u1 = __shfl_up(i1, d, 64);
            if (lane >= d) { i0 += u0; i1 += u1; }
        }
        unsigned long long e0 = i0 - p0, e1 = i1 - p1;  // exclusive, field-wise
        unsigned long long t0 = __shfl(i0, 63, 64), t1 = __shfl(i1, 63, 64);
        if (lane == 0) {
#pragma unroll
            for (int c = 0; c < 4; c++) {
                wbase_s[wv][c]     = (int)((t0 >> (c << 4)) & 0xFFFF);
                wbase_s[wv][c + 4] = (int)((t1 >> (c << 4)) & 0xFFFF);
            }
        }
        __syncthreads();
        if (tid < NC) {  // scan wave totals -> wave bases + condition totals
            int acc = 0;
            for (int w2 = 0; w2 < 4; w2++) { int t = wbase_s[w2][tid]; wbase_s[w2][tid] = acc; acc += t; }
            cnt_s[tid] = acc;
        }
        __syncthreads();
        if (tid < NC) {  // off = exclusive scan over conditions
            int acc = 0;
            for (int c2 = 0; c2 < tid; c2++) acc += cnt_s[c2];
            off_s[tid] = acc;
        }
        __syncthreads();
        if (tid < 32) wbase_s[tid >> 3][tid & 7] += off_s[tid & 7];  // fold cond offset in
        __syncthreads();

        // primary tile slots: condition c pinned to XCD c (tid<8, parallel)
        if (tid < NC) {
            int c = tid, n = cnt_s[c];
            int tc = (n + 127) >> 7;
            int prim = tc < SLOTS ? tc : SLOTS;
            for (int t = 0; t < prim; t++) {
                int* e = xmeta + (c * SLOTS + t) * 3;
                int rc = n - t * 128; if (rc > 128) rc = 128;
                e[0] = c; e[1] = off_s[c] + t * 128; e[2] = rc;
            }
            used_s[c] = prim;
            novf_s[c] = tc - prim;
        }
        // bias_sum[d] = sum_c b[c][d]
#pragma unroll
        for (int k = 0; k < DIM / 256; k++) {
            int d = tid + k * 256;
            float s = 0.f;
#pragma unroll
            for (int c = 0; c < NC; c++) s += b[c * DIM + d];
            bias_sum[d] = s;
        }
        __syncthreads();

        // overflow tiles (only if some condition >2048 rows) -> free slots
        if (tid == 0) {
            int k = 0;
            for (int c = 0; c < NC; c++) {
                for (int t = 0; t < novf_s[c]; t++) {
                    for (;;) {
                        int xx = k >> 4, s = k & (SLOTS - 1); k++;
                        if (s >= used_s[xx]) {
                            int* e = xmeta + (xx * SLOTS + s) * 3;
                            int rc = cnt_s[c] - (SLOTS + t) * 128; if (rc > 128) rc = 128;
                            e[0] = c; e[1] = off_s[c] + (SLOTS + t) * 128; e[2] = rc;
                            break;
                        }
                    }
                }
            }
        }
        // scatter rows (deterministic: scan-derived positions)
        unsigned long long r0 = 0, r1 = 0;
#pragma unroll
        for (int j = 0; j < per; j++) {
            int id = myid[j];
            int sh = (id & 3) << 4;
            unsigned long long run = (id < 4) ? r0 : r1;
            unsigned long long exc = (id < 4) ? e0 : e1;
            int p = wbase_s[wv][id] + (int)((exc >> sh) & 0xFFFF) + (int)((run >> sh) & 0xFFFF);
            row_list[p] = base + j;
            unsigned long long one = 1ull << sh;
            if (id < 4) r0 += one; else r1 += one;
        }
    } else {
        // ---------- fp32 -> bf16 conversion, x then W, grid-stride ----------
        int nb = gridDim.x - 1;
        for (size_t i = (size_t)(blockIdx.x - 1) * 256 + threadIdx.x; i < XCH + WCH;
             i += (size_t)nb * 256) {
            const float4* s;
            bf16* d;
            if (i < XCH) { s = (const float4*)x + 2 * i; d = xb + 8 * i; }
            else { size_t j = i - XCH; s = (const float4*)W + 2 * j; d = wb + 8 * j; }
            float4 a = s[0], c4 = s[1];
            bf16x8 o;
            o[0] = (bf16)a.x;  o[1] = (bf16)a.y;  o[2] = (bf16)a.z;  o[3] = (bf16)a.w;
            o[4] = (bf16)c4.x; o[5] = (bf16)c4.y; o[6] = (bf16)c4.z; o[7] = (bf16)c4.w;
            *(bf16x8*)d = o;
        }
    }
}

// ---------------- grouped GEMM: 128x128, BK=64, counted-vmcnt 2-phase ------
// LDS slot (r, cb16) holds global col (cb16 ^ (r&7)); staged via pre-swizzled
// global source col, read back with matching XOR (rule 21: both sides).
__global__ __launch_bounds__(256, 2) void gemm_kernel(
    const bf16* __restrict__ xb, const bf16* __restrict__ wb,
    const float* __restrict__ bias_sum, const int* __restrict__ row_list,
    const int* __restrict__ xmeta, float* __restrict__ out) {
    int xcd = blockIdx.x, slot = blockIdx.y, colt = blockIdx.z;
    const int* e = xmeta + (xcd * SLOTS + slot) * 3;
    int cond = e[0], rstart = e[1], rcnt = e[2];
    if (rcnt == 0) return;
    int col0 = colt * 128;

    __shared__ bf16 lds[2][2][128 * 64];  // 64 KB

    int tid  = threadIdx.x;
    int lane = tid & 63;
    int w    = tid >> 6;
    int wr   = w >> 1;
    int wc   = w & 1;
    int srow = lane >> 3;
    int scol = ((lane & 7) ^ srow) * 8;   // swizzled global source col (elems)

    const bf16 *aS[4], *bS[4];
#pragma unroll
    for (int i = 0; i < 4; i++) {
        int tr = w * 32 + i * 8 + srow;
        int rr = (tr < rcnt) ? tr : 0;                       // clamp pad rows
        int grow = row_list[rstart + rr];
        aS[i] = xb + (size_t)grow * DIM + scol;
        bS[i] = wb + (size_t)cond * DIM * DIM + (size_t)(col0 + tr) * DIM + scol;
    }

    f32x4 acc[4][4];
#pragma unroll
    for (int m = 0; m < 4; m++)
#pragma unroll
        for (int n = 0; n < 4; n++) acc[m][n] = (f32x4){0.f, 0.f, 0.f, 0.f};

    int fr = lane & 15;
    int fq = lane >> 4;
    int off0 = (fq * 16) ^ ((fr & 7) << 4);
    int off1 = off0 ^ 64;

    auto stage = [&](int buf, int k0) {
#pragma unroll
        for (int i = 0; i < 4; i++) {
            __builtin_amdgcn_global_load_lds((gbl_vp)(aS[i] + k0),
                                             (lds_vp)(&lds[buf][0][(w * 32 + i * 8) * 64]),
                                             16, 0, 0);
            __builtin_amdgcn_global_load_lds((gbl_vp)(bS[i] + k0),
                                             (lds_vp)(&lds[buf][1][(w * 32 + i * 8) * 64]),
                                             16, 0, 0);
        }
    };

    stage(0, 0);
    stage(1, 64);

    const int NT = DIM / 64;  // 16
    for (int t = 0; t < NT; ++t) {
        if (t < NT - 1) asm volatile("s_waitcnt vmcnt(8)" ::: "memory");
        else            asm volatile("s_waitcnt vmcnt(0)" ::: "memory");
        __builtin_amdgcn_s_barrier();

        const char* baseA = (const char*)&lds[t & 1][0][0] + (wr * 64 + fr) * 128;
        const char* baseB = (const char*)&lds[t & 1][1][0] + (wc * 64 + fr) * 128;
#pragma unroll
        for (int kk = 0; kk < 2; ++kk) {
            int ofs = kk ? off1 : off0;
            bf16x8 af[4], bv[4];
#pragma unroll
            for (int m = 0; m < 4; m++) af[m] = *(const bf16x8*)(baseA + m * 2048 + ofs);
#pragma unroll
            for (int n = 0; n < 4; n++) bv[n] = *(const bf16x8*)(baseB + n * 2048 + ofs);
            __builtin_amdgcn_s_setprio(1);
#pragma unroll
            for (int m = 0; m < 4; m++)
#pragma unroll
                for (int n = 0; n < 4; n++)
                    acc[m][n] = __builtin_amdgcn_mfma_f32_16x16x32_bf16(
                        af[m], bv[n], acc[m][n], 0, 0, 0);
            __builtin_amdgcn_s_setprio(0);
        }

        asm volatile("s_waitcnt lgkmcnt(0)" ::: "memory");
        __builtin_amdgcn_s_barrier();
        if (t + 2 < NT) stage(t & 1, (t + 2) * 64);
    }

    float bias[4];
#pragma unroll
    for (int n = 0; n < 4; n++) bias[n] = bias_sum[col0 + wc * 64 + n * 16 + fr];
#pragma unroll
    for (int m = 0; m < 4; m++) {
#pragma unroll
        for (int i = 0; i < 4; i++) {
            int rl = wr * 64 + m * 16 + fq * 4 + i;
            if (rl < rcnt) {
                int grow = row_list[rstart + rl];
                float* op = out + (size_t)grow * DIM + col0 + wc * 64 + fr;
#pragma unroll
                for (int n = 0; n < 4; n++) op[n * 16] = acc[m][n][i] + bias[n];
            }
        }
    }
}

// ---------------- naive fallback (only if ws too small) --------------------
__global__ void naive_kernel(const float* __restrict__ x, const int* __restrict__ ids,
                             const float* __restrict__ W, const float* __restrict__ b,
                             float* __restrict__ out) {
    int row = blockIdx.x;
    int c = ids[row];
    __shared__ float xs[DIM];
    for (int i = threadIdx.x; i < DIM; i += 256) xs[i] = x[(size_t)row * DIM + i];
    __syncthreads();
    const float* Wc = W + (size_t)c * DIM * DIM;
    for (int o = threadIdx.x; o < DIM; o += 256) {
        float s = 0.f;
        const float* wrp = Wc + (size_t)o * DIM;
        for (int i = 0; i < DIM; i++) s += xs[i] * wrp[i];
        float bs = 0.f;
#pragma unroll
        for (int cc = 0; cc < NC; cc++) bs += b[cc * DIM + o];
        out[(size_t)row * DIM + o] = s + bs;
    }
}

extern "C" void kernel_launch(void* const* d_in, const int* in_sizes, int n_in,
                              void* d_out, int out_size, void* d_ws, size_t ws_size,
                              hipStream_t stream) {
    const float* x   = (const float*)d_in[0];
    const int*   ids = (const int*)d_in[1];
    const float* W   = (const float*)d_in[2];
    const float* b   = (const float*)d_in[3];
    float*       out = (float*)d_out;

    size_t xb_off   = 0;
    size_t xb_sz    = (size_t)B_ROWS * DIM * 2;
    size_t wb_off   = (xb_off + xb_sz + 255) & ~(size_t)255;
    size_t wb_sz    = (size_t)NC * DIM * DIM * 2;
    size_t bias_off = (wb_off + wb_sz + 255) & ~(size_t)255;
    size_t rl_off   = (bias_off + DIM * 4 + 255) & ~(size_t)255;
    size_t meta_off = (rl_off + B_ROWS * 4 + 255) & ~(size_t)255;
    size_t need     = meta_off + (size_t)NXCD * SLOTS * 3 * 4;

    if (ws_size < need) {
        naive_kernel<<<dim3(B_ROWS), dim3(256), 0, stream>>>(x, ids, W, b, out);
        return;
    }

    char* ws = (char*)d_ws;
    bf16*  xb       = (bf16*)(ws + xb_off);
    bf16*  wbf      = (bf16*)(ws + wb_off);
    float* bias_sum = (float*)(ws + bias_off);
    int*   row_list = (int*)(ws + rl_off);
    int*   xmeta    = (int*)(ws + meta_off);

    prep_kernel<<<dim3(2049), dim3(256), 0, stream>>>(x, W, ids, b, xb, wbf,
                                                      row_list, xmeta, bias_sum);
    gemm_kernel<<<dim3(NXCD, SLOTS, 8), dim3(256), 0, stream>>>(xb, wbf, bias_sum,
                                                                row_list, xmeta, out);
}

// Round 5
// 62.882 us; speedup vs baseline: 1.5970x; 1.3067x over previous
//
#include <hip/hip_runtime.h>
#include <hip/hip_bf16.h>
#include <cstdint>

#define B_ROWS 8192
#define DIM    1024
#define NC     8
#define NXCD   8
#define SLOTS  16   // per-XCD row-tile slots

typedef __bf16 bf16;
typedef __bf16 bf16x4 __attribute__((ext_vector_type(4)));
typedef __bf16 bf16x8 __attribute__((ext_vector_type(8)));
typedef float  f32x4  __attribute__((ext_vector_type(4)));

typedef __attribute__((address_space(3))) void* lds_vp;
typedef const __attribute__((address_space(1))) void* gbl_vp;

// ---------------- route: 1024 threads, scan-based, no atomics --------------
__global__ __launch_bounds__(1024) void route_kernel(
    const int* __restrict__ ids, const float* __restrict__ b,
    int* __restrict__ row_list, int* __restrict__ xmeta,
    float* __restrict__ bias_sum) {
    __shared__ int wtot_s[16][NC];
    __shared__ int cnt_s[NC];
    __shared__ int off_s[NC];
    __shared__ int used_s[NXCD];
    __shared__ int novf_s[NC];
    int tid = threadIdx.x, lane = tid & 63, wv = tid >> 6;
    const int per = B_ROWS / 1024;  // 8
    int base = tid * per;

    if (tid < NXCD * SLOTS) xmeta[tid * 3 + 2] = 0;

    // load my 8 ids (two int4), count into packed 16-bit fields
    const int4* idv = (const int4*)(ids + base);
    int4 v0 = idv[0], v1 = idv[1];
    int myid[8] = {v0.x, v0.y, v0.z, v0.w, v1.x, v1.y, v1.z, v1.w};
    unsigned long long p0 = 0, p1 = 0;
#pragma unroll
    for (int q = 0; q < 8; q++) {
        int id = myid[q];
        unsigned long long one = 1ull << ((id & 3) << 4);
        if (id < 4) p0 += one; else p1 += one;
    }
    // inclusive field-wise scan across the wave
    unsigned long long i0 = p0, i1 = p1;
#pragma unroll
    for (int d = 1; d < 64; d <<= 1) {
        unsigned long long u0 = __shfl_up(i0, d, 64);
        unsigned long long u1 = __shfl_up(i1, d, 64);
        if (lane >= d) { i0 += u0; i1 += u1; }
    }
    unsigned long long e0 = i0 - p0, e1 = i1 - p1;
    unsigned long long t0 = __shfl(i0, 63, 64), t1 = __shfl(i1, 63, 64);
    if (lane == 0) {
#pragma unroll
        for (int c = 0; c < 4; c++) {
            wtot_s[wv][c]     = (int)((t0 >> (c << 4)) & 0xFFFF);
            wtot_s[wv][c + 4] = (int)((t1 >> (c << 4)) & 0xFFFF);
        }
    }
    __syncthreads();
    if (tid < NC) {  // cross-wave exclusive scan + condition totals
        int acc = 0;
        for (int w2 = 0; w2 < 16; w2++) { int t = wtot_s[w2][tid]; wtot_s[w2][tid] = acc; acc += t; }
        cnt_s[tid] = acc;
    }
    __syncthreads();
    if (tid < NC) {
        int acc = 0;
        for (int c2 = 0; c2 < tid; c2++) acc += cnt_s[c2];
        off_s[tid] = acc;
    }
    __syncthreads();
    if (tid < 16 * NC) wtot_s[tid >> 3][tid & 7] += off_s[tid & 7];
    __syncthreads();

    // primary tile slots: condition c pinned to XCD c
    if (tid < NC) {
        int c = tid, n = cnt_s[c];
        int tc = (n + 127) >> 7;
        int prim = tc < SLOTS ? tc : SLOTS;
        for (int t = 0; t < prim; t++) {
            int* e = xmeta + (c * SLOTS + t) * 3;
            int rc = n - t * 128; if (rc > 128) rc = 128;
            e[0] = c; e[1] = off_s[c] + t * 128; e[2] = rc;
        }
        used_s[c] = prim;
        novf_s[c] = tc - prim;
    }
    // bias_sum[d] = sum_c b[c][d]  (DIM == blockDim)
    {
        float s = 0.f;
#pragma unroll
        for (int c = 0; c < NC; c++) s += b[c * DIM + tid];
        bias_sum[tid] = s;
    }
    __syncthreads();

    // overflow tiles (condition with >SLOTS*128 rows) -> free slots
    if (tid == 0) {
        int k = 0;
        for (int c = 0; c < NC; c++) {
            for (int t = 0; t < novf_s[c]; t++) {
                for (;;) {
                    int xx = k >> 4, s = k & (SLOTS - 1); k++;
                    if (s >= used_s[xx]) {
                        int* e = xmeta + (xx * SLOTS + s) * 3;
                        int rc = cnt_s[c] - (SLOTS + t) * 128; if (rc > 128) rc = 128;
                        e[0] = c; e[1] = off_s[c] + (SLOTS + t) * 128; e[2] = rc;
                        break;
                    }
                }
            }
        }
    }
    // scatter rows (deterministic scan-derived positions)
    unsigned long long r0 = 0, r1 = 0;
#pragma unroll
    for (int j = 0; j < per; j++) {
        int id = myid[j];
        int sh = (id & 3) << 4;
        unsigned long long run = (id < 4) ? r0 : r1;
        unsigned long long exc = (id < 4) ? e0 : e1;
        int p = wtot_s[wv][id] + (int)((exc >> sh) & 0xFFFF) + (int)((run >> sh) & 0xFFFF);
        row_list[p] = base + j;
        unsigned long long one = 1ull << sh;
        if (id < 4) r0 += one; else r1 += one;
    }
}

// ---------------- conversion: dense float4 loads, 8 per thread -------------
#define XF4 (B_ROWS * DIM / 4)      // 2097152 float4 in x
__global__ __launch_bounds__(1024) void cvt_kernel(
    const float* __restrict__ x, const float* __restrict__ W,
    bf16* __restrict__ xb, bf16* __restrict__ wb) {
    size_t base = (size_t)blockIdx.x * 8192 + threadIdx.x;
    const float4* src;
    bf16* dst;
    if (base < (size_t)XF4) { src = (const float4*)x; dst = xb; }
    else                    { src = (const float4*)W; dst = wb; base -= (size_t)XF4; }
    float4 v[8];
#pragma unroll
    for (int k = 0; k < 8; k++) v[k] = src[base + (size_t)k * 1024];
#pragma unroll
    for (int k = 0; k < 8; k++) {
        bf16x4 o;
        o[0] = (bf16)v[k].x; o[1] = (bf16)v[k].y;
        o[2] = (bf16)v[k].z; o[3] = (bf16)v[k].w;
        *(bf16x4*)(dst + 4 * (base + (size_t)k * 1024)) = o;
    }
}

// ---------------- grouped GEMM: 128x128, BK=64, counted-vmcnt 2-phase ------
// (unchanged from round 3/4: XOR-swizzled staging + counted vmcnt + setprio)
__global__ __launch_bounds__(256, 2) void gemm_kernel(
    const bf16* __restrict__ xb, const bf16* __restrict__ wb,
    const float* __restrict__ bias_sum, const int* __restrict__ row_list,
    const int* __restrict__ xmeta, float* __restrict__ out) {
    int xcd = blockIdx.x, slot = blockIdx.y, colt = blockIdx.z;
    const int* e = xmeta + (xcd * SLOTS + slot) * 3;
    int cond = e[0], rstart = e[1], rcnt = e[2];
    if (rcnt == 0) return;
    int col0 = colt * 128;

    __shared__ bf16 lds[2][2][128 * 64];  // 64 KB

    int tid  = threadIdx.x;
    int lane = tid & 63;
    int w    = tid >> 6;
    int wr   = w >> 1;
    int wc   = w & 1;
    int srow = lane >> 3;
    int scol = ((lane & 7) ^ srow) * 8;

    const bf16 *aS[4], *bS[4];
#pragma unroll
    for (int i = 0; i < 4; i++) {
        int tr = w * 32 + i * 8 + srow;
        int rr = (tr < rcnt) ? tr : 0;
        int grow = row_list[rstart + rr];
        aS[i] = xb + (size_t)grow * DIM + scol;
        bS[i] = wb + (size_t)cond * DIM * DIM + (size_t)(col0 + tr) * DIM + scol;
    }

    f32x4 acc[4][4];
#pragma unroll
    for (int m = 0; m < 4; m++)
#pragma unroll
        for (int n = 0; n < 4; n++) acc[m][n] = (f32x4){0.f, 0.f, 0.f, 0.f};

    int fr = lane & 15;
    int fq = lane >> 4;
    int off0 = (fq * 16) ^ ((fr & 7) << 4);
    int off1 = off0 ^ 64;

    auto stage = [&](int buf, int k0) {
#pragma unroll
        for (int i = 0; i < 4; i++) {
            __builtin_amdgcn_global_load_lds((gbl_vp)(aS[i] + k0),
                                             (lds_vp)(&lds[buf][0][(w * 32 + i * 8) * 64]),
                                             16, 0, 0);
            __builtin_amdgcn_global_load_lds((gbl_vp)(bS[i] + k0),
                                             (lds_vp)(&lds[buf][1][(w * 32 + i * 8) * 64]),
                                             16, 0, 0);
        }
    };

    stage(0, 0);
    stage(1, 64);

    const int NT = DIM / 64;  // 16
    for (int t = 0; t < NT; ++t) {
        if (t < NT - 1) asm volatile("s_waitcnt vmcnt(8)" ::: "memory");
        else            asm volatile("s_waitcnt vmcnt(0)" ::: "memory");
        __builtin_amdgcn_s_barrier();

        const char* baseA = (const char*)&lds[t & 1][0][0] + (wr * 64 + fr) * 128;
        const char* baseB = (const char*)&lds[t & 1][1][0] + (wc * 64 + fr) * 128;
#pragma unroll
        for (int kk = 0; kk < 2; ++kk) {
            int ofs = kk ? off1 : off0;
            bf16x8 af[4], bv[4];
#pragma unroll
            for (int m = 0; m < 4; m++) af[m] = *(const bf16x8*)(baseA + m * 2048 + ofs);
#pragma unroll
            for (int n = 0; n < 4; n++) bv[n] = *(const bf16x8*)(baseB + n * 2048 + ofs);
            __builtin_amdgcn_s_setprio(1);
#pragma unroll
            for (int m = 0; m < 4; m++)
#pragma unroll
                for (int n = 0; n < 4; n++)
                    acc[m][n] = __builtin_amdgcn_mfma_f32_16x16x32_bf16(
                        af[m], bv[n], acc[m][n], 0, 0, 0);
            __builtin_amdgcn_s_setprio(0);
        }

        asm volatile("s_waitcnt lgkmcnt(0)" ::: "memory");
        __builtin_amdgcn_s_barrier();
        if (t + 2 < NT) stage(t & 1, (t + 2) * 64);
    }

    float bias[4];
#pragma unroll
    for (int n = 0; n < 4; n++) bias[n] = bias_sum[col0 + wc * 64 + n * 16 + fr];
#pragma unroll
    for (int m = 0; m < 4; m++) {
#pragma unroll
        for (int i = 0; i < 4; i++) {
            int rl = wr * 64 + m * 16 + fq * 4 + i;
            if (rl < rcnt) {
                int grow = row_list[rstart + rl];
                float* op = out + (size_t)grow * DIM + col0 + wc * 64 + fr;
#pragma unroll
                for (int n = 0; n < 4; n++) op[n * 16] = acc[m][n][i] + bias[n];
            }
        }
    }
}

// ---------------- naive fallback (only if ws too small) --------------------
__global__ void naive_kernel(const float* __restrict__ x, const int* __restrict__ ids,
                             const float* __restrict__ W, const float* __restrict__ b,
                             float* __restrict__ out) {
    int row = blockIdx.x;
    int c = ids[row];
    __shared__ float xs[DIM];
    for (int i = threadIdx.x; i < DIM; i += 256) xs[i] = x[(size_t)row * DIM + i];
    __syncthreads();
    const float* Wc = W + (size_t)c * DIM * DIM;
    for (int o = threadIdx.x; o < DIM; o += 256) {
        float s = 0.f;
        const float* wrp = Wc + (size_t)o * DIM;
        for (int i = 0; i < DIM; i++) s += xs[i] * wrp[i];
        float bs = 0.f;
#pragma unroll
        for (int cc = 0; cc < NC; cc++) bs += b[cc * DIM + o];
        out[(size_t)row * DIM + o] = s + bs;
    }
}

extern "C" void kernel_launch(void* const* d_in, const int* in_sizes, int n_in,
                              void* d_out, int out_size, void* d_ws, size_t ws_size,
                              hipStream_t stream) {
    const float* x   = (const float*)d_in[0];
    const int*   ids = (const int*)d_in[1];
    const float* W   = (const float*)d_in[2];
    const float* b   = (const float*)d_in[3];
    float*       out = (float*)d_out;

    size_t xb_off   = 0;
    size_t xb_sz    = (size_t)B_ROWS * DIM * 2;
    size_t wb_off   = (xb_off + xb_sz + 255) & ~(size_t)255;
    size_t wb_sz    = (size_t)NC * DIM * DIM * 2;
    size_t bias_off = (wb_off + wb_sz + 255) & ~(size_t)255;
    size_t rl_off   = (bias_off + DIM * 4 + 255) & ~(size_t)255;
    size_t meta_off = (rl_off + B_ROWS * 4 + 255) & ~(size_t)255;
    size_t need     = meta_off + (size_t)NXCD * SLOTS * 3 * 4;

    if (ws_size < need) {
        naive_kernel<<<dim3(B_ROWS), dim3(256), 0, stream>>>(x, ids, W, b, out);
        return;
    }

    char* ws = (char*)d_ws;
    bf16*  xb       = (bf16*)(ws + xb_off);
    bf16*  wbf      = (bf16*)(ws + wb_off);
    float* bias_sum = (float*)(ws + bias_off);
    int*   row_list = (int*)(ws + rl_off);
    int*   xmeta    = (int*)(ws + meta_off);

    route_kernel<<<dim3(1), dim3(1024), 0, stream>>>(ids, b, row_list, xmeta, bias_sum);
    cvt_kernel<<<dim3(512), dim3(1024), 0, stream>>>(x, W, xb, wbf);
    gemm_kernel<<<dim3(NXCD, SLOTS, 8), dim3(256), 0, stream>>>(xb, wbf, bias_sum,
                                                                row_list, xmeta, out);
}